// Round 5
// baseline (292.398 us; speedup 1.0000x reference)
//
#include <hip/hip_runtime.h>
#include <hip/hip_bf16.h>

// Problem constants (B=2, H=16, L=2048, D=E=64)
#define BH_  32
#define H_   16
#define L_   2048
#define D_   64
#define NC_  32      // number of 64-row chunks per (b,h)
#define STR  72      // LDS row stride in halfs (144 B: 16B-aligned rows, 2-way banks)

typedef _Float16 half8 __attribute__((ext_vector_type(8)));
typedef _Float16 half4 __attribute__((ext_vector_type(4)));
typedef _Float16 half2v __attribute__((ext_vector_type(2)));
typedef float    floatx4 __attribute__((ext_vector_type(4)));

#define MFMA(a, b, c) __builtin_amdgcn_mfma_f32_16x16x32_f16((a), (b), (c), 0, 0, 0)

// MFMA operand fragment from a row-major [rows][K] LDS matrix (stride STR).
// lane layout: row = row0 + (lane&15), k = k0 + (lane>>4)*8 .. +7 (one b128)
__device__ __forceinline__ half8 ldfrag(const _Float16* p, int row0, int k0) {
    const int lane = threadIdx.x & 63;
    const _Float16* q = p + (row0 + (lane & 15)) * STR + k0 + ((lane >> 4) << 3);
    return *(const half8*)q;
}

// ---------------------------------------------------------------------------
// kA: block (c, bh):
//   kf = relu(K_chunk @ Wk)  (Wk transposed inline from global, L2-hot)
//   S^T_c[e][f] f16, z_c[f] f32, side outputs kf[n][f] f16, V^T[e][n] f16.
//   LAST block per bh (device-scope ticket) then does the exclusive prefix
//   scan of S^T and z for that bh in-place (fp32 running sum, f16 store —
//   numerically identical to the former kp kernel).
// ---------------------------------------------------------------------------
__global__ __launch_bounds__(256, 2)
void ka_fused(const float* __restrict__ K, const float* __restrict__ V,
              const float* __restrict__ Wk,
              _Float16* __restrict__ Ss, float* __restrict__ zc,
              _Float16* __restrict__ kf16, _Float16* __restrict__ VT16,
              int* __restrict__ cnt) {
    __shared__ __align__(16) _Float16 sK  [64 * STR]; // K [n][d] -> kf [n][f]
    __shared__ __align__(16) _Float16 sWkT[64 * STR]; // Wk^T [e][d]
    __shared__ __align__(16) _Float16 sVT [64 * STR]; // V^T [e][n]
    __shared__ __align__(16) _Float16 sKfT[64 * STR]; // kf^T [f][n]
    __shared__ int sLast;

    const int c = blockIdx.x, bh = blockIdx.y, h = bh & (H_ - 1);
    const int tid = threadIdx.x, lane = tid & 63, w = tid >> 6;
    const int quad = lane >> 4, cl = lane & 15;

    const float* Kg = K + ((size_t)bh * L_ + c * 64) * D_;
    const float* Vg = V + ((size_t)bh * L_ + c * 64) * D_;
    const float* Wkg = Wk + (size_t)h * 4096;
    const size_t cb = (size_t)bh * NC_ + c;

    for (int i = 0; i < 4; ++i) {
        int flat = i * 1024 + tid * 4;
        int r = flat >> 6, e0 = flat & 63;
        float4 kv = *(const float4*)(Kg + flat);
        half4 kh = { (_Float16)kv.x, (_Float16)kv.y, (_Float16)kv.z, (_Float16)kv.w };
        *(half4*)(sK + r * STR + e0) = kh;
        float4 vv = *(const float4*)(Vg + flat);        // V^T scatter
        sVT[(e0 + 0) * STR + r] = (_Float16)vv.x;
        sVT[(e0 + 1) * STR + r] = (_Float16)vv.y;
        sVT[(e0 + 2) * STR + r] = (_Float16)vv.z;
        sVT[(e0 + 3) * STR + r] = (_Float16)vv.w;
        float4 wv = *(const float4*)(Wkg + flat);       // Wk^T scatter (d=r, e=e0+j)
        sWkT[(e0 + 0) * STR + r] = (_Float16)wv.x;
        sWkT[(e0 + 1) * STR + r] = (_Float16)wv.y;
        sWkT[(e0 + 2) * STR + r] = (_Float16)wv.z;
        sWkT[(e0 + 3) * STR + r] = (_Float16)wv.w;
    }
    __syncthreads();

    half8 ak0 = ldfrag(sK, w * 16, 0), ak1 = ldfrag(sK, w * 16, 32);
    for (int et = 0; et < 4; ++et) {
        floatx4 acc = {0.f, 0.f, 0.f, 0.f};
        acc = MFMA(ak0, ldfrag(sWkT, et * 16, 0),  acc);
        acc = MFMA(ak1, ldfrag(sWkT, et * 16, 32), acc);
        #pragma unroll
        for (int r = 0; r < 4; ++r) {
            float v = acc[r] > 0.f ? acc[r] : 0.f;
            _Float16 hv = (_Float16)v;
            int n = w * 16 + quad * 4 + r, f = et * 16 + cl;
            sKfT[f * STR + n] = hv;
            sK  [n * STR + f] = hv;
        }
    }
    __syncthreads();

    for (int i = 0; i < 2; ++i) {          // side outputs (vector copies)
        int flat = i * 2048 + tid * 8;
        int rr = flat >> 6, c0 = flat & 63;
        *(half8*)(kf16 + cb * 4096 + flat) = *(const half8*)(sK  + rr * STR + c0);
        *(half8*)(VT16 + cb * 4096 + flat) = *(const half8*)(sVT + rr * STR + c0);
    }
    if (tid < 64) {                        // z_c[f]
        float s = 0.f;
        #pragma unroll
        for (int j = 0; j < 8; ++j) {
            half8 hv = *(const half8*)(sKfT + tid * STR + j * 8);
            #pragma unroll
            for (int t = 0; t < 8; ++t) s += (float)hv[t];
        }
        zc[cb * 64 + tid] = s;
    }

    // S^T[e][f] f16: A = V^T (m=e rows), B = kf^T (n=f rows), k = n
    _Float16* So = Ss + cb * 4096;
    half8 av0 = ldfrag(sVT, w * 16, 0), av1 = ldfrag(sVT, w * 16, 32);
    for (int et = 0; et < 4; ++et) {
        floatx4 acc = {0.f, 0.f, 0.f, 0.f};
        acc = MFMA(av0, ldfrag(sKfT, et * 16, 0),  acc);
        acc = MFMA(av1, ldfrag(sKfT, et * 16, 32), acc);
        #pragma unroll
        for (int r = 0; r < 4; ++r)
            So[(w * 16 + quad * 4 + r) * 64 + et * 16 + cl] = (_Float16)acc[r];
    }

    // ---- ticket: last block of this bh does the prefix scan ----
    __threadfence();                       // release this block's stores
    __syncthreads();
    if (tid == 0) sLast = (atomicAdd(&cnt[bh], 1) == NC_ - 1) ? 1 : 0;
    __syncthreads();
    if (!sLast) return;
    __threadfence();                       // acquire other blocks' stores

    // exclusive prefix over chunks: S^T rows as packed f16 pairs (8 dwords/thread)
    uint32_t* S32 = (uint32_t*)(Ss + (size_t)bh * NC_ * 4096);
    float run[16];
    #pragma unroll
    for (int j = 0; j < 16; ++j) run[j] = 0.f;
    for (int cc = 0; cc < NC_; ++cc) {
        uint32_t* p = S32 + cc * 2048 + tid * 8;
        uint4 a = *(uint4*)p, b = *(uint4*)(p + 4);
        uint32_t in[8] = {a.x, a.y, a.z, a.w, b.x, b.y, b.z, b.w};
        uint32_t out[8];
        #pragma unroll
        for (int j = 0; j < 8; ++j) {
            half2v hv = *(half2v*)&in[j];
            half2v o; o[0] = (_Float16)run[2*j]; o[1] = (_Float16)run[2*j+1];
            out[j] = *(uint32_t*)&o;
            run[2*j]   += (float)hv[0];
            run[2*j+1] += (float)hv[1];
        }
        uint4 oa = {out[0], out[1], out[2], out[3]};
        uint4 ob = {out[4], out[5], out[6], out[7]};
        *(uint4*)p = oa;
        *(uint4*)(p + 4) = ob;
    }
    if (tid < 64) {                        // z exclusive prefix (f32)
        float* zb = zc + (size_t)bh * NC_ * 64;
        float r = 0.f;
        #pragma unroll
        for (int cc = 0; cc < NC_; ++cc) {
            float v = zb[cc * 64 + tid];
            zb[cc * 64 + tid] = r;
            r += v;
        }
    }
}

// ---------------------------------------------------------------------------
// kB: block (c, bh). ONE barrier. Wq split/transposed inline (L2-hot).
// qf split-precision (6 MFMAs/tile), stored single-f16 (row-proportional
// error cancels in num/den). P reuses sQl. S^T/V^T B-fragments direct
// global->reg in the O loop.
// ---------------------------------------------------------------------------
__global__ __launch_bounds__(256, 3)
void kb_attn(const float* __restrict__ Q, const float* __restrict__ Wq,
             const _Float16* __restrict__ kf16, const _Float16* __restrict__ VT16,
             const _Float16* __restrict__ Ss, const float* __restrict__ zs,
             float* __restrict__ Out) {
    __shared__ __align__(16) _Float16 sQh[64 * STR]; // Q hi [m][d] -> qf f16 [m][f]
    __shared__ __align__(16) _Float16 sQl[64 * STR]; // Q lo [m][d] -> P [m][n]
    __shared__ __align__(16) _Float16 sWh[64 * STR]; // Wq hi^T [e][d]
    __shared__ __align__(16) _Float16 sWl[64 * STR]; // Wq lo^T [e][d]
    __shared__ __align__(16) _Float16 sKf[64 * STR]; // kf [n][f]
    __shared__ float sZ[64];

    const int c = blockIdx.x, bh = blockIdx.y, h = bh & (H_ - 1);
    const int tid = threadIdx.x, lane = tid & 63, w = tid >> 6;
    const int quad = lane >> 4, cl = lane & 15;

    const float* Qg = Q + ((size_t)bh * L_ + c * 64) * D_;
    const float* Wqg = Wq + (size_t)h * 4096;
    const size_t cb = (size_t)bh * NC_ + c;
    const _Float16* Sgp = Ss   + cb * 4096;   // S_prefix^T [e][f], stride 64
    const _Float16* Vgp = VT16 + cb * 4096;   // V^T [e][n], stride 64

    for (int i = 0; i < 4; ++i) {
        int flat = i * 1024 + tid * 4;
        int r = flat >> 6, e0 = flat & 63;
        float4 qv = *(const float4*)(Qg + flat);       // Q hi/lo split
        half4 qh, ql;
        #pragma unroll
        for (int j = 0; j < 4; ++j) {
            float x = (&qv.x)[j];
            _Float16 hi = (_Float16)x;
            qh[j] = hi; ql[j] = (_Float16)(x - (float)hi);
        }
        *(half4*)(sQh + r * STR + e0) = qh;
        *(half4*)(sQl + r * STR + e0) = ql;
        float4 wv = *(const float4*)(Wqg + flat);      // Wq hi/lo split + transpose
        #pragma unroll
        for (int j = 0; j < 4; ++j) {
            float x = (&wv.x)[j];
            _Float16 hi = (_Float16)x;
            sWh[(e0 + j) * STR + r] = hi;
            sWl[(e0 + j) * STR + r] = (_Float16)(x - (float)hi);
        }
    }
    for (int i = 0; i < 2; ++i) {
        int flat = i * 2048 + tid * 8;
        int rr = flat >> 6, c0 = flat & 63;
        *(half8*)(sKf + rr * STR + c0) = *(const half8*)(kf16 + cb * 4096 + flat);
    }
    if (tid < 64) sZ[tid] = zs[cb * 64 + tid];
    __syncthreads();   // the ONLY barrier

    // qf stage (~fp32): relu; dq from fp32 accs; store qf single f16 (own rows)
    half8 aqh0 = ldfrag(sQh, w * 16, 0), aqh1 = ldfrag(sQh, w * 16, 32);
    half8 aql0 = ldfrag(sQl, w * 16, 0), aql1 = ldfrag(sQl, w * 16, 32);
    float dq[4] = {0.f, 0.f, 0.f, 0.f};
    for (int et = 0; et < 4; ++et) {
        half8 bh0 = ldfrag(sWh, et * 16, 0), bh1 = ldfrag(sWh, et * 16, 32);
        half8 bl0 = ldfrag(sWl, et * 16, 0), bl1 = ldfrag(sWl, et * 16, 32);
        floatx4 acc = {0.f, 0.f, 0.f, 0.f};
        acc = MFMA(aqh0, bh0, acc);
        acc = MFMA(aqh1, bh1, acc);
        acc = MFMA(aqh0, bl0, acc);
        acc = MFMA(aqh1, bl1, acc);
        acc = MFMA(aql0, bh0, acc);
        acc = MFMA(aql1, bh1, acc);
        float zv = sZ[et * 16 + cl];
        #pragma unroll
        for (int r = 0; r < 4; ++r) {
            float v = acc[r] > 0.f ? acc[r] : 0.f;
            dq[r] += v * zv;
            sQh[(w * 16 + quad * 4 + r) * STR + et * 16 + cl] = (_Float16)v;
        }
    }
    #pragma unroll
    for (int r = 0; r < 4; ++r) {
        dq[r] += __shfl_xor(dq[r], 1);
        dq[r] += __shfl_xor(dq[r], 2);
        dq[r] += __shfl_xor(dq[r], 4);
        dq[r] += __shfl_xor(dq[r], 8);
    }

    // P stage: intra-chunk causal scores (own rows of P = sQl)
    half8 qh0 = ldfrag(sQh, w * 16, 0), qh1 = ldfrag(sQh, w * 16, 32);
    _Float16* P = sQl;
    float rs[4] = {0.f, 0.f, 0.f, 0.f};
    float inv[4];
    for (int nt = 0; nt <= w; ++nt) {
        floatx4 acc = {0.f, 0.f, 0.f, 0.f};
        acc = MFMA(qh0, ldfrag(sKf, nt * 16, 0),  acc);
        acc = MFMA(qh1, ldfrag(sKf, nt * 16, 32), acc);
        #pragma unroll
        for (int r = 0; r < 4; ++r) {
            float v = acc[r];
            if (nt == w && cl > quad * 4 + r) v = 0.f;   // causal mask (diag tile)
            rs[r] += v;
            P[(w * 16 + quad * 4 + r) * STR + nt * 16 + cl] = (_Float16)v;
        }
    }
    for (int nt = w + 1; nt < 4; ++nt) {
        #pragma unroll
        for (int r = 0; r < 4; ++r)
            P[(w * 16 + quad * 4 + r) * STR + nt * 16 + cl] = (_Float16)0.f;
    }
    #pragma unroll
    for (int r = 0; r < 4; ++r) {
        float s = rs[r];
        s += __shfl_xor(s, 1);
        s += __shfl_xor(s, 2);
        s += __shfl_xor(s, 4);
        s += __shfl_xor(s, 8);
        inv[r] = 1.f / (s + dq[r] + 1e-6f);
    }

    // O stage: O = qf@S^T' + P@V; S^T/V^T fragments direct global->reg
    half8 p0 = ldfrag(P, w * 16, 0), p1 = ldfrag(P, w * 16, 32);
    float* Og = Out + ((size_t)bh * L_ + c * 64) * D_;
    for (int et = 0; et < 4; ++et) {
        const _Float16* srow = Sgp + (et * 16 + cl) * 64 + quad * 8;
        const _Float16* vrow = Vgp + (et * 16 + cl) * 64 + quad * 8;
        half8 s0 = *(const half8*)(srow);
        half8 s1 = *(const half8*)(srow + 32);
        half8 v0 = *(const half8*)(vrow);
        half8 v1 = *(const half8*)(vrow + 32);
        floatx4 acc = {0.f, 0.f, 0.f, 0.f};
        acc = MFMA(qh0, s0, acc);
        acc = MFMA(qh1, s1, acc);
        acc = MFMA(p0,  v0, acc);
        acc = MFMA(p1,  v1, acc);
        #pragma unroll
        for (int r = 0; r < 4; ++r)
            Og[(w * 16 + quad * 4 + r) * 64 + et * 16 + cl] = acc[r] * inv[r];
    }
}

// ---------------------------------------------------------------------------
extern "C" void kernel_launch(void* const* d_in, const int* in_sizes, int n_in,
                              void* d_out, int out_size, void* d_ws, size_t ws_size,
                              hipStream_t stream) {
    const float* Q  = (const float*)d_in[0];
    const float* K  = (const float*)d_in[1];
    const float* V  = (const float*)d_in[2];
    const float* Wq = (const float*)d_in[3];
    const float* Wk = (const float*)d_in[4];
    float* Out = (float*)d_out;

    _Float16* Ss   = (_Float16*)d_ws;                            // 8 MB  (S^T f16)
    float*    zc   = (float*)(Ss + (size_t)BH_ * NC_ * 4096);    // 256 KB
    _Float16* kf16 = (_Float16*)(zc + (size_t)BH_ * NC_ * 64);   // 8 MB
    _Float16* VT16 = kf16 + (size_t)BH_ * NC_ * 4096;            // 8 MB
    int*      cnt  = (int*)(VT16 + (size_t)BH_ * NC_ * 4096);    // 128 B

    hipMemsetAsync(cnt, 0, BH_ * sizeof(int), stream);
    dim3 grid(NC_, BH_);
    hipLaunchKernelGGL(ka_fused, grid, dim3(256), 0, stream, K, V, Wk, Ss, zc, kf16, VT16, cnt);
    hipLaunchKernelGGL(kb_attn, grid, dim3(256), 0, stream, Q, Wq, kf16, VT16, Ss, zc, Out);
}

// Round 6
// 120.685 us; speedup vs baseline: 2.4228x; 2.4228x over previous
//
#include <hip/hip_runtime.h>
#include <hip/hip_bf16.h>

// Problem constants (B=2, H=16, L=2048, D=E=64)
#define BH_  32
#define H_   16
#define L_   2048
#define D_   64
#define NC_  32      // number of 64-row chunks per (b,h)
#define STR  72      // LDS row stride in halfs (144 B: 16B-aligned rows, 2-way banks)

typedef _Float16 half8 __attribute__((ext_vector_type(8)));
typedef _Float16 half4 __attribute__((ext_vector_type(4)));
typedef _Float16 half2v __attribute__((ext_vector_type(2)));
typedef float    floatx4 __attribute__((ext_vector_type(4)));

#define MFMA(a, b, c) __builtin_amdgcn_mfma_f32_16x16x32_f16((a), (b), (c), 0, 0, 0)

// MFMA operand fragment from a row-major [rows][K] LDS matrix (stride STR).
// lane layout: row = row0 + (lane&15), k = k0 + (lane>>4)*8 .. +7 (one b128)
__device__ __forceinline__ half8 ldfrag(const _Float16* p, int row0, int k0) {
    const int lane = threadIdx.x & 63;
    const _Float16* q = p + (row0 + (lane & 15)) * STR + k0 + ((lane >> 4) << 3);
    return *(const half8*)q;
}

// ---------------------------------------------------------------------------
// ka: block (c, bh):  (NO fences/tickets — R5 showed agent-scope fences cost
// ~170 µs in L2 writebacks on non-coherent per-XCD L2s.)
//   kf = relu(K_chunk @ Wk)  (Wk transposed inline from global, L2-hot)
//   S^T_c[e][f] f16, z_c[f] f32; side outputs kf[n][f] f16, V^T[e][n] f16.
// ---------------------------------------------------------------------------
__global__ __launch_bounds__(256, 2)
void ka_chunksum(const float* __restrict__ K, const float* __restrict__ V,
                 const float* __restrict__ Wk,
                 _Float16* __restrict__ Ss, float* __restrict__ zc,
                 _Float16* __restrict__ kf16, _Float16* __restrict__ VT16) {
    __shared__ __align__(16) _Float16 sK  [64 * STR]; // K [n][d] -> kf [n][f]
    __shared__ __align__(16) _Float16 sWkT[64 * STR]; // Wk^T [e][d]
    __shared__ __align__(16) _Float16 sVT [64 * STR]; // V^T [e][n]
    __shared__ __align__(16) _Float16 sKfT[64 * STR]; // kf^T [f][n]

    const int c = blockIdx.x, bh = blockIdx.y, h = bh & (H_ - 1);
    const int tid = threadIdx.x, lane = tid & 63, w = tid >> 6;
    const int quad = lane >> 4, cl = lane & 15;

    const float* Kg = K + ((size_t)bh * L_ + c * 64) * D_;
    const float* Vg = V + ((size_t)bh * L_ + c * 64) * D_;
    const float* Wkg = Wk + (size_t)h * 4096;
    const size_t cb = (size_t)bh * NC_ + c;

    for (int i = 0; i < 4; ++i) {
        int flat = i * 1024 + tid * 4;
        int r = flat >> 6, e0 = flat & 63;
        float4 kv = *(const float4*)(Kg + flat);
        half4 kh = { (_Float16)kv.x, (_Float16)kv.y, (_Float16)kv.z, (_Float16)kv.w };
        *(half4*)(sK + r * STR + e0) = kh;
        float4 vv = *(const float4*)(Vg + flat);        // V^T scatter
        sVT[(e0 + 0) * STR + r] = (_Float16)vv.x;
        sVT[(e0 + 1) * STR + r] = (_Float16)vv.y;
        sVT[(e0 + 2) * STR + r] = (_Float16)vv.z;
        sVT[(e0 + 3) * STR + r] = (_Float16)vv.w;
        float4 wv = *(const float4*)(Wkg + flat);       // Wk^T scatter (d=r, e=e0+j)
        sWkT[(e0 + 0) * STR + r] = (_Float16)wv.x;
        sWkT[(e0 + 1) * STR + r] = (_Float16)wv.y;
        sWkT[(e0 + 2) * STR + r] = (_Float16)wv.z;
        sWkT[(e0 + 3) * STR + r] = (_Float16)wv.w;
    }
    __syncthreads();

    half8 ak0 = ldfrag(sK, w * 16, 0), ak1 = ldfrag(sK, w * 16, 32);
    for (int et = 0; et < 4; ++et) {
        floatx4 acc = {0.f, 0.f, 0.f, 0.f};
        acc = MFMA(ak0, ldfrag(sWkT, et * 16, 0),  acc);
        acc = MFMA(ak1, ldfrag(sWkT, et * 16, 32), acc);
        #pragma unroll
        for (int r = 0; r < 4; ++r) {
            float v = acc[r] > 0.f ? acc[r] : 0.f;
            _Float16 hv = (_Float16)v;
            int n = w * 16 + quad * 4 + r, f = et * 16 + cl;
            sKfT[f * STR + n] = hv;
            sK  [n * STR + f] = hv;
        }
    }
    __syncthreads();

    for (int i = 0; i < 2; ++i) {          // side outputs (vector copies)
        int flat = i * 2048 + tid * 8;
        int rr = flat >> 6, c0 = flat & 63;
        *(half8*)(kf16 + cb * 4096 + flat) = *(const half8*)(sK  + rr * STR + c0);
        *(half8*)(VT16 + cb * 4096 + flat) = *(const half8*)(sVT + rr * STR + c0);
    }
    if (tid < 64) {                        // z_c[f]
        float s = 0.f;
        #pragma unroll
        for (int j = 0; j < 8; ++j) {
            half8 hv = *(const half8*)(sKfT + tid * STR + j * 8);
            #pragma unroll
            for (int t = 0; t < 8; ++t) s += (float)hv[t];
        }
        zc[cb * 64 + tid] = s;
    }

    // S^T[e][f] f16: A = V^T (m=e rows), B = kf^T (n=f rows), k = n
    _Float16* So = Ss + cb * 4096;
    half8 av0 = ldfrag(sVT, w * 16, 0), av1 = ldfrag(sVT, w * 16, 32);
    for (int et = 0; et < 4; ++et) {
        floatx4 acc = {0.f, 0.f, 0.f, 0.f};
        acc = MFMA(av0, ldfrag(sKfT, et * 16, 0),  acc);
        acc = MFMA(av1, ldfrag(sKfT, et * 16, 32), acc);
        #pragma unroll
        for (int r = 0; r < 4; ++r)
            So[(w * 16 + quad * 4 + r) * 64 + et * 16 + cl] = (_Float16)acc[r];
    }
}

// ---------------------------------------------------------------------------
// kp: in-place EXCLUSIVE prefix over chunks. S rows as packed uint32
// (2 f16 cols), fp32 running sum, f16 store. z in f32.
// ---------------------------------------------------------------------------
__global__ __launch_bounds__(64)
void kp_prefix(_Float16* __restrict__ Ss, float* __restrict__ zc) {
    const int bid = blockIdx.x, t = threadIdx.x;
    if (bid < BH_ * 32) {
        const int bh = bid >> 5, dq = bid & 31;
        uint32_t* S32 = (uint32_t*)Ss;
        size_t base = (size_t)bh * NC_ * 2048 + dq * 64 + t;
        float r0 = 0.f, r1 = 0.f;
        #pragma unroll
        for (int c = 0; c < NC_; ++c) {
            uint32_t u = S32[base + (size_t)c * 2048];
            half2v hv = *(half2v*)&u;
            float v0 = (float)hv[0], v1 = (float)hv[1];
            half2v o; o[0] = (_Float16)r0; o[1] = (_Float16)r1;
            S32[base + (size_t)c * 2048] = *(uint32_t*)&o;
            r0 += v0; r1 += v1;
        }
    } else {
        const int bh = bid - BH_ * 32;
        size_t base = (size_t)bh * NC_ * 64 + t;
        float run = 0.f;
        #pragma unroll
        for (int c = 0; c < NC_; ++c) {
            float v = zc[base + c * 64];
            zc[base + c * 64] = run;
            run += v;
        }
    }
}

// ---------------------------------------------------------------------------
// kb: block (c, bh). ONE barrier. Wq split/transposed inline (L2-hot).
// qf split-precision (6 MFMAs/tile), stored single-f16 (row-proportional
// error cancels in num/den). P reuses sQl. S^T/V^T B-fragments direct
// global->reg in the O loop.
// ---------------------------------------------------------------------------
__global__ __launch_bounds__(256, 3)
void kb_attn(const float* __restrict__ Q, const float* __restrict__ Wq,
             const _Float16* __restrict__ kf16, const _Float16* __restrict__ VT16,
             const _Float16* __restrict__ Ss, const float* __restrict__ zs,
             float* __restrict__ Out) {
    __shared__ __align__(16) _Float16 sQh[64 * STR]; // Q hi [m][d] -> qf f16 [m][f]
    __shared__ __align__(16) _Float16 sQl[64 * STR]; // Q lo [m][d] -> P [m][n]
    __shared__ __align__(16) _Float16 sWh[64 * STR]; // Wq hi^T [e][d]
    __shared__ __align__(16) _Float16 sWl[64 * STR]; // Wq lo^T [e][d]
    __shared__ __align__(16) _Float16 sKf[64 * STR]; // kf [n][f]
    __shared__ float sZ[64];

    const int c = blockIdx.x, bh = blockIdx.y, h = bh & (H_ - 1);
    const int tid = threadIdx.x, lane = tid & 63, w = tid >> 6;
    const int quad = lane >> 4, cl = lane & 15;

    const float* Qg = Q + ((size_t)bh * L_ + c * 64) * D_;
    const float* Wqg = Wq + (size_t)h * 4096;
    const size_t cb = (size_t)bh * NC_ + c;
    const _Float16* Sgp = Ss   + cb * 4096;   // S_prefix^T [e][f], stride 64
    const _Float16* Vgp = VT16 + cb * 4096;   // V^T [e][n], stride 64

    for (int i = 0; i < 4; ++i) {
        int flat = i * 1024 + tid * 4;
        int r = flat >> 6, e0 = flat & 63;
        float4 qv = *(const float4*)(Qg + flat);       // Q hi/lo split
        half4 qh, ql;
        #pragma unroll
        for (int j = 0; j < 4; ++j) {
            float x = (&qv.x)[j];
            _Float16 hi = (_Float16)x;
            qh[j] = hi; ql[j] = (_Float16)(x - (float)hi);
        }
        *(half4*)(sQh + r * STR + e0) = qh;
        *(half4*)(sQl + r * STR + e0) = ql;
        float4 wv = *(const float4*)(Wqg + flat);      // Wq hi/lo split + transpose
        #pragma unroll
        for (int j = 0; j < 4; ++j) {
            float x = (&wv.x)[j];
            _Float16 hi = (_Float16)x;
            sWh[(e0 + j) * STR + r] = hi;
            sWl[(e0 + j) * STR + r] = (_Float16)(x - (float)hi);
        }
    }
    for (int i = 0; i < 2; ++i) {
        int flat = i * 2048 + tid * 8;
        int rr = flat >> 6, c0 = flat & 63;
        *(half8*)(sKf + rr * STR + c0) = *(const half8*)(kf16 + cb * 4096 + flat);
    }
    if (tid < 64) sZ[tid] = zs[cb * 64 + tid];
    __syncthreads();   // the ONLY barrier

    // qf stage (~fp32): relu; dq from fp32 accs; store qf single f16 (own rows)
    half8 aqh0 = ldfrag(sQh, w * 16, 0), aqh1 = ldfrag(sQh, w * 16, 32);
    half8 aql0 = ldfrag(sQl, w * 16, 0), aql1 = ldfrag(sQl, w * 16, 32);
    float dq[4] = {0.f, 0.f, 0.f, 0.f};
    for (int et = 0; et < 4; ++et) {
        half8 bh0 = ldfrag(sWh, et * 16, 0), bh1 = ldfrag(sWh, et * 16, 32);
        half8 bl0 = ldfrag(sWl, et * 16, 0), bl1 = ldfrag(sWl, et * 16, 32);
        floatx4 acc = {0.f, 0.f, 0.f, 0.f};
        acc = MFMA(aqh0, bh0, acc);
        acc = MFMA(aqh1, bh1, acc);
        acc = MFMA(aqh0, bl0, acc);
        acc = MFMA(aqh1, bl1, acc);
        acc = MFMA(aql0, bh0, acc);
        acc = MFMA(aql1, bh1, acc);
        float zv = sZ[et * 16 + cl];
        #pragma unroll
        for (int r = 0; r < 4; ++r) {
            float v = acc[r] > 0.f ? acc[r] : 0.f;
            dq[r] += v * zv;
            sQh[(w * 16 + quad * 4 + r) * STR + et * 16 + cl] = (_Float16)v;
        }
    }
    #pragma unroll
    for (int r = 0; r < 4; ++r) {
        dq[r] += __shfl_xor(dq[r], 1);
        dq[r] += __shfl_xor(dq[r], 2);
        dq[r] += __shfl_xor(dq[r], 4);
        dq[r] += __shfl_xor(dq[r], 8);
    }

    // P stage: intra-chunk causal scores (own rows of P = sQl)
    half8 qh0 = ldfrag(sQh, w * 16, 0), qh1 = ldfrag(sQh, w * 16, 32);
    _Float16* P = sQl;
    float rs[4] = {0.f, 0.f, 0.f, 0.f};
    float inv[4];
    for (int nt = 0; nt <= w; ++nt) {
        floatx4 acc = {0.f, 0.f, 0.f, 0.f};
        acc = MFMA(qh0, ldfrag(sKf, nt * 16, 0),  acc);
        acc = MFMA(qh1, ldfrag(sKf, nt * 16, 32), acc);
        #pragma unroll
        for (int r = 0; r < 4; ++r) {
            float v = acc[r];
            if (nt == w && cl > quad * 4 + r) v = 0.f;   // causal mask (diag tile)
            rs[r] += v;
            P[(w * 16 + quad * 4 + r) * STR + nt * 16 + cl] = (_Float16)v;
        }
    }
    for (int nt = w + 1; nt < 4; ++nt) {
        #pragma unroll
        for (int r = 0; r < 4; ++r)
            P[(w * 16 + quad * 4 + r) * STR + nt * 16 + cl] = (_Float16)0.f;
    }
    #pragma unroll
    for (int r = 0; r < 4; ++r) {
        float s = rs[r];
        s += __shfl_xor(s, 1);
        s += __shfl_xor(s, 2);
        s += __shfl_xor(s, 4);
        s += __shfl_xor(s, 8);
        inv[r] = 1.f / (s + dq[r] + 1e-6f);
    }

    // O stage: O = qf@S^T' + P@V; S^T/V^T fragments direct global->reg
    half8 p0 = ldfrag(P, w * 16, 0), p1 = ldfrag(P, w * 16, 32);
    float* Og = Out + ((size_t)bh * L_ + c * 64) * D_;
    for (int et = 0; et < 4; ++et) {
        const _Float16* srow = Sgp + (et * 16 + cl) * 64 + quad * 8;
        const _Float16* vrow = Vgp + (et * 16 + cl) * 64 + quad * 8;
        half8 s0 = *(const half8*)(srow);
        half8 s1 = *(const half8*)(srow + 32);
        half8 v0 = *(const half8*)(vrow);
        half8 v1 = *(const half8*)(vrow + 32);
        floatx4 acc = {0.f, 0.f, 0.f, 0.f};
        acc = MFMA(qh0, s0, acc);
        acc = MFMA(qh1, s1, acc);
        acc = MFMA(p0,  v0, acc);
        acc = MFMA(p1,  v1, acc);
        #pragma unroll
        for (int r = 0; r < 4; ++r)
            Og[(w * 16 + quad * 4 + r) * 64 + et * 16 + cl] = acc[r] * inv[r];
    }
}

// ---------------------------------------------------------------------------
extern "C" void kernel_launch(void* const* d_in, const int* in_sizes, int n_in,
                              void* d_out, int out_size, void* d_ws, size_t ws_size,
                              hipStream_t stream) {
    const float* Q  = (const float*)d_in[0];
    const float* K  = (const float*)d_in[1];
    const float* V  = (const float*)d_in[2];
    const float* Wq = (const float*)d_in[3];
    const float* Wk = (const float*)d_in[4];
    float* Out = (float*)d_out;

    _Float16* Ss   = (_Float16*)d_ws;                            // 8 MB  (S^T f16)
    float*    zc   = (float*)(Ss + (size_t)BH_ * NC_ * 4096);    // 256 KB
    _Float16* kf16 = (_Float16*)(zc + (size_t)BH_ * NC_ * 64);   // 8 MB
    _Float16* VT16 = kf16 + (size_t)BH_ * NC_ * 4096;            // 8 MB

    dim3 grid(NC_, BH_);
    hipLaunchKernelGGL(ka_chunksum, grid, dim3(256), 0, stream, K, V, Wk, Ss, zc, kf16, VT16);
    hipLaunchKernelGGL(kp_prefix, dim3(BH_ * 32 + BH_), dim3(64), 0, stream, Ss, zc);
    hipLaunchKernelGGL(kb_attn, grid, dim3(256), 0, stream, Q, Wq, kf16, VT16, Ss, zc, Out);
}